// Round 14
// baseline (180.712 us; speedup 1.0000x reference)
//
#include <hip/hip_runtime.h>

#define HH 384
#define WW 384
#define HWP (HH * WW)   // 147456
#define DD 64
#define BB 2
#define NG2 8           // 8 phases, 8 channels each

#define TX 16
#define TY 8            // tile 16x8; thread owns px (y0+ty, y0+ty+4), ty in 0..3
#define LR 24           // TY + 16 halo rows
#define LC 32           // TX + 16 halo cols
#define LN (LR * LC)    // 768 slots (uint4) = 12.3 KB/buffer; x3 = 36.9 KB
#define NT 64           // ONE wave per block -> no barriers anywhere
#define SPT (LN / NT)   // 12 staging slots/thread, exact
#define NBX (WW / TX)   // 24
#define NBY (HH / TY)   // 48
#define NWG (NBX * NBY * BB)   // 2304 = 8 * 288

typedef __fp16 h2v __attribute__((ext_vector_type(2)));
union h4 { uint2 u; h2v h[2]; };

#if __has_builtin(__builtin_amdgcn_fdot2)
#define DOT4(acc, a, b)                                           \
    acc = __builtin_amdgcn_fdot2((a).h[0], (b).h[0], acc, false);   \
    acc = __builtin_amdgcn_fdot2((a).h[1], (b).h[1], acc, false)
#else
#define DOT4(acc, a, b)                                     \
    acc = fmaf((float)(a).h[0].x, (float)(b).h[0].x, acc);   \
    acc = fmaf((float)(a).h[0].y, (float)(b).h[0].y, acc);   \
    acc = fmaf((float)(a).h[1].x, (float)(b).h[1].x, acc);   \
    acc = fmaf((float)(a).h[1].y, (float)(b).h[1].y, acc)
#endif

// async global->LDS, 16B per lane (vmcnt-counted)
__device__ __forceinline__ void gl_lds16(const uint4* g, uint4* l) {
    __builtin_amdgcn_global_load_lds(
        (const __attribute__((address_space(1))) unsigned int*)(const void*)g,
        (__attribute__((address_space(3))) unsigned int*)(void*)l, 16, 0, 0);
}

#define FENCE() asm volatile("" ::: "memory")

// K1: stats + repack to f16 8-channel planes hp4[b][g2][y][x] (16 B / px).
// smm dropped: ssd recomputes channel-sum from staged f16 (error ~3e-4).
__global__ __launch_bounds__(256) void stats_pack_k(const float* __restrict__ des,
                                                    uint4* __restrict__ hp4,
                                                    float* __restrict__ ssq) {
    int idx = blockIdx.x * 256 + threadIdx.x;        // 0 .. 294911
    int b = idx / HWP;
    int p = idx - b * HWP;
    const float* base = des + (size_t)b * DD * HWP + p;
    uint4* hb = hp4 + (size_t)b * NG2 * HWP + p;
    float ss = 0.f;
#pragma unroll 2
    for (int g = 0; g < NG2; ++g) {
        float v0 = base[(size_t)(8 * g + 0) * HWP];
        float v1 = base[(size_t)(8 * g + 1) * HWP];
        float v2 = base[(size_t)(8 * g + 2) * HWP];
        float v3 = base[(size_t)(8 * g + 3) * HWP];
        float v4 = base[(size_t)(8 * g + 4) * HWP];
        float v5 = base[(size_t)(8 * g + 5) * HWP];
        float v6 = base[(size_t)(8 * g + 6) * HWP];
        float v7 = base[(size_t)(8 * g + 7) * HWP];
        ss = fmaf(v0, v0, ss); ss = fmaf(v1, v1, ss);
        ss = fmaf(v2, v2, ss); ss = fmaf(v3, v3, ss);
        ss = fmaf(v4, v4, ss); ss = fmaf(v5, v5, ss);
        ss = fmaf(v6, v6, ss); ss = fmaf(v7, v7, ss);
        h4 a, c;
        a.h[0] = __builtin_amdgcn_cvt_pkrtz(v0, v1);
        a.h[1] = __builtin_amdgcn_cvt_pkrtz(v2, v3);
        c.h[0] = __builtin_amdgcn_cvt_pkrtz(v4, v5);
        c.h[1] = __builtin_amdgcn_cvt_pkrtz(v6, v7);
        uint4 w; w.x = a.u.x; w.y = a.u.y; w.z = c.u.x; w.w = c.u.y;
        hb[(size_t)g * HWP] = w;
    }
    ssq[idx] = ss;
}

// K2: dilated 5x5 dot stencil, 2 px/thread (y, y+4). Single-wave blocks,
// barrier-free, THREE-buffer 3-deep async pipeline: vmcnt(24) waits only for
// loads issued 2 phases ago (~2x latency cover vs R13's 2-deep).
__global__ __launch_bounds__(NT) void ssd_k(const uint4* __restrict__ hp4,
                                            const float* __restrict__ ssq,
                                            float* __restrict__ out) {
    __shared__ uint4 lds[3][LN];   // 36,864 B
    const int tid = threadIdx.x;           // 0..63
    const int tx = tid & 15;               // 0..15
    const int ty = tid >> 4;               // 0..3

    // XCD-aware bijective swizzle (2304 = 8 * 288)
    int bid = blockIdx.x;
    int swz = (bid & 7) * 288 + (bid >> 3);
    int b  = swz / (NBX * NBY);
    int r0 = swz % (NBX * NBY);
    int by = r0 / NBX;
    int bx = r0 - by * NBX;
    const int x0 = bx * TX, y0 = by * TY;
    const int x = x0 + tx;
    const int y = y0 + ty;                 // px A; px B = y + 4

    // Clamped global offsets for this thread's 12 staging slots (768 = 12*64)
    int goff[SPT];
#pragma unroll
    for (int k = 0; k < SPT; ++k) {
        int i = tid + NT * k;
        int r = i / LC, c = i - (i / LC) * LC;
        int gy = y0 + r - 8; gy = gy < 0 ? 0 : (gy > HH - 1 ? HH - 1 : gy);
        int gx = x0 + c - 8; gx = gx < 0 ? 0 : (gx > WW - 1 ? WW - 1 : gx);
        goff[k] = gy * WW + gx;
    }

    const uint4* hb = hp4 + (size_t)b * NG2 * HWP;

    // issue 12 async global->LDS loads for channel-plane g into lds[bb]
    auto STAGE = [&](int g, int bb) {
        const uint4* p = hb + (size_t)g * HWP;
#pragma unroll
        for (int k = 0; k < SPT; ++k)
            gl_lds16(p + goff[k], &lds[bb][tid + NT * k]);
    };

    float accA[25], accB[25];
#pragma unroll
    for (int n = 0; n < 25; ++n) { accA[n] = 0.f; accB[n] = 0.f; }
    float smA = 0.f, smB = 0.f;    // channel sums of own centers (replaces smm)

    h4 ONE;
    { h2v one2; one2.x = (__fp16)1.f; one2.y = (__fp16)1.f;
      ONE.h[0] = one2; ONE.h[1] = one2; }

    const int base = ty * LC + tx;
    auto COMPUTE = [&](int bb) {
        const uint4* L = lds[bb];
        uint4 cc0 = L[base + 8 * LC + 8];    // center px A
        uint4 cc1 = L[base + 12 * LC + 8];   // center px B
        h4 cA0, cA1, cB0, cB1;
        cA0.u.x = cc0.x; cA0.u.y = cc0.y; cA1.u.x = cc0.z; cA1.u.y = cc0.w;
        cB0.u.x = cc1.x; cB0.u.y = cc1.y; cB1.u.x = cc1.z; cB1.u.y = cc1.w;
        DOT4(smA, cA0, ONE); DOT4(smA, cA1, ONE);
        DOT4(smB, cB0, ONE); DOT4(smB, cB1, ONE);
        __builtin_amdgcn_s_setprio(1);
#pragma unroll
        for (int m = 0; m < 6; ++m)
#pragma unroll
            for (int j = 0; j < 5; ++j) {
                uint4 v = L[base + (4 * m) * LC + 4 * j];
                h4 va, vb;
                va.u.x = v.x; va.u.y = v.y; vb.u.x = v.z; vb.u.y = v.w;
                if (m < 5) {
                    int n = m * 5 + j;
                    DOT4(accA[n], cA0, va);
                    DOT4(accA[n], cA1, vb);
                }
                if (m >= 1) {
                    int n = (m - 1) * 5 + j;
                    DOT4(accB[n], cB0, va);
                    DOT4(accB[n], cB1, vb);
                }
            }
        __builtin_amdgcn_s_setprio(0);
    };

    // 3-deep barrier-free pipeline (single wave):
    //   phase g: vmcnt(24) [own loads done; g+1,g+2's in flight] -> COMPUTE(g%3)
    //            -> lgkmcnt(0) -> STAGE(g+3 -> g%3)
    STAGE(0, 0);
    STAGE(1, 1);
    STAGE(2, 2);
#pragma unroll
    for (int g = 0; g < NG2; ++g) {
        if (g < NG2 - 2)      { asm volatile("s_waitcnt vmcnt(24)" ::: "memory"); }
        else if (g == NG2 - 2){ asm volatile("s_waitcnt vmcnt(12)" ::: "memory"); }
        else                  { asm volatile("s_waitcnt vmcnt(0)"  ::: "memory"); }
        FENCE();
        COMPUTE(g % 3);
        FENCE();
        if (g + 3 < NG2) {
            asm volatile("s_waitcnt lgkmcnt(0)" ::: "memory");
            STAGE(g + 3, g % 3);
        }
    }

    // epilogue: stage ssq tile (f32) into buffer 0 (all DMA retired)
    asm volatile("s_waitcnt lgkmcnt(0)" ::: "memory");
    float* lsq = (float*)&lds[0][0];   // 768 floats (3 KB)
    {
        const float* sp = ssq + (size_t)b * HWP;
        float r[SPT];
#pragma unroll
        for (int k = 0; k < SPT; ++k) r[k] = sp[goff[k]];
#pragma unroll
        for (int k = 0; k < SPT; ++k) lsq[tid + NT * k] = r[k];
    }
    FENCE();

    float sv[6][5];
#pragma unroll
    for (int m = 0; m < 6; ++m)
#pragma unroll
        for (int j = 0; j < 5; ++j)
            sv[m][j] = lsq[base + (4 * m) * LC + 4 * j];

    // clamped tap coords for exact-zero self taps
    int yc[6], xc[5];
#pragma unroll
    for (int m = 0; m < 6; ++m) {
        int yy = y - 8 + 4 * m; yc[m] = yy < 0 ? 0 : (yy > HH - 1 ? HH - 1 : yy);
    }
#pragma unroll
    for (int j = 0; j < 5; ++j) {
        int xx = x - 8 + 4 * j; xc[j] = xx < 0 ? 0 : (xx > WW - 1 ? WW - 1 : xx);
    }

#pragma unroll
    for (int a = 0; a < 2; ++a) {
        const int py = y + 4 * a;
        const float* acc = a ? accB : accA;
        float sm = a ? smB : smA;
        float ssA = sv[2 + a][2];
        float mu = sm * (1.0f / 64);
        float var = ssA * (1.0f / 64) - mu * mu;
        float sabs = sqrtf(fmaxf(var, 0.f));
        float L = 0.f;
#pragma unroll
        for (int m = 0; m < 5; ++m)
#pragma unroll
            for (int j = 0; j < 5; ++j) {
                float ssB = sv[m + a][j];
                float d2 = fmaxf(ssA + ssB - 2.f * acc[m * 5 + j], 0.f);
                float sq = sqrtf(d2);
                L += (yc[m + a] == py && xc[j] == x) ? 0.f : sq;
            }
        float srel = L * (1.0f / 25);
        float sraw = sabs * srel;
        out[(size_t)b * HWP + py * WW + x] = sraw / (sraw + 1.f);
    }
}

extern "C" void kernel_launch(void* const* d_in, const int* in_sizes, int n_in,
                              void* d_out, int out_size, void* d_ws, size_t ws_size,
                              hipStream_t stream) {
    const float* des = (const float*)d_in[0];
    float* out = (float*)d_out;

    uint4* hp4 = (uint4*)d_ws;                                   // BB*NG2*HWP uint4
    float* ssq = (float*)(hp4 + (size_t)BB * NG2 * HWP);         // BB*HWP

    stats_pack_k<<<dim3((BB * HWP) / 256), dim3(256), 0, stream>>>(des, hp4, ssq);
    ssd_k<<<dim3(NWG), dim3(NT), 0, stream>>>(hp4, ssq, out);
}

// Round 15
// 52.999 us; speedup vs baseline: 3.4097x; 3.4097x over previous
//
#include <hip/hip_runtime.h>

#define HH 384
#define WW 384
#define HWP (HH * WW)   // 147456
#define DD 64
#define BB 2
#define NG2 8           // 8 phases, 8 channels each

#define TX 16
#define TY 8            // tile 16x8; thread owns px (y0+ty, y0+ty+4), ty in 0..3
#define LR 24           // TY + 16 halo rows
#define LC 32           // TX + 16 halo cols
#define LN (LR * LC)    // 768 slots (uint4) = 12.3 KB/buffer; x3 = 36.9 KB
#define NT 64           // ONE wave per block -> no barriers anywhere
#define SPT (LN / NT)   // 12 staging slots/thread, exact
#define NBX (WW / TX)   // 24
#define NBY (HH / TY)   // 48
#define NWG (NBX * NBY * BB)   // 2304 = 8 * 288

typedef __fp16 h2v __attribute__((ext_vector_type(2)));
union h4 { uint2 u; h2v h[2]; };

#if __has_builtin(__builtin_amdgcn_fdot2)
#define DOT4(acc, a, b)                                           \
    acc = __builtin_amdgcn_fdot2((a).h[0], (b).h[0], acc, false);   \
    acc = __builtin_amdgcn_fdot2((a).h[1], (b).h[1], acc, false)
#else
#define DOT4(acc, a, b)                                     \
    acc = fmaf((float)(a).h[0].x, (float)(b).h[0].x, acc);   \
    acc = fmaf((float)(a).h[0].y, (float)(b).h[0].y, acc);   \
    acc = fmaf((float)(a).h[1].x, (float)(b).h[1].x, acc);   \
    acc = fmaf((float)(a).h[1].y, (float)(b).h[1].y, acc)
#endif

// async global->LDS, 16B per lane (vmcnt-counted)
__device__ __forceinline__ void gl_lds16(const uint4* g, uint4* l) {
    __builtin_amdgcn_global_load_lds(
        (const __attribute__((address_space(1))) unsigned int*)(const void*)g,
        (__attribute__((address_space(3))) unsigned int*)(void*)l, 16, 0, 0);
}

#define FENCE() asm volatile("" ::: "memory")

// K1: stats + repack to f16 8-channel planes hp4[b][g2][y][x] (16 B / px).
// smm dropped: ssd recomputes channel-sum from staged f16 (error ~3e-4).
__global__ __launch_bounds__(256) void stats_pack_k(const float* __restrict__ des,
                                                    uint4* __restrict__ hp4,
                                                    float* __restrict__ ssq) {
    int idx = blockIdx.x * 256 + threadIdx.x;        // 0 .. 294911
    int b = idx / HWP;
    int p = idx - b * HWP;
    const float* base = des + (size_t)b * DD * HWP + p;
    uint4* hb = hp4 + (size_t)b * NG2 * HWP + p;
    float ss = 0.f;
#pragma unroll 2
    for (int g = 0; g < NG2; ++g) {
        float v0 = base[(size_t)(8 * g + 0) * HWP];
        float v1 = base[(size_t)(8 * g + 1) * HWP];
        float v2 = base[(size_t)(8 * g + 2) * HWP];
        float v3 = base[(size_t)(8 * g + 3) * HWP];
        float v4 = base[(size_t)(8 * g + 4) * HWP];
        float v5 = base[(size_t)(8 * g + 5) * HWP];
        float v6 = base[(size_t)(8 * g + 6) * HWP];
        float v7 = base[(size_t)(8 * g + 7) * HWP];
        ss = fmaf(v0, v0, ss); ss = fmaf(v1, v1, ss);
        ss = fmaf(v2, v2, ss); ss = fmaf(v3, v3, ss);
        ss = fmaf(v4, v4, ss); ss = fmaf(v5, v5, ss);
        ss = fmaf(v6, v6, ss); ss = fmaf(v7, v7, ss);
        h4 a, c;
        a.h[0] = __builtin_amdgcn_cvt_pkrtz(v0, v1);
        a.h[1] = __builtin_amdgcn_cvt_pkrtz(v2, v3);
        c.h[0] = __builtin_amdgcn_cvt_pkrtz(v4, v5);
        c.h[1] = __builtin_amdgcn_cvt_pkrtz(v6, v7);
        uint4 w; w.x = a.u.x; w.y = a.u.y; w.z = c.u.x; w.w = c.u.y;
        hb[(size_t)g * HWP] = w;
    }
    ssq[idx] = ss;
}

// K2: dilated 5x5 dot stencil, 2 px/thread (y, y+4). Single-wave blocks,
// barrier-free, 3-buffer 3-deep async DMA pipeline. Phase loop MUST stay
// "#pragma unroll 1" (full unroll -> 256 VGPR + scratch spill, R14).
__global__ __launch_bounds__(NT) void ssd_k(const uint4* __restrict__ hp4,
                                            const float* __restrict__ ssq,
                                            float* __restrict__ out) {
    __shared__ uint4 lds[3][LN];   // 36,864 B
    const int tid = threadIdx.x;           // 0..63
    const int tx = tid & 15;               // 0..15
    const int ty = tid >> 4;               // 0..3

    // XCD-aware bijective swizzle (2304 = 8 * 288)
    int bid = blockIdx.x;
    int swz = (bid & 7) * 288 + (bid >> 3);
    int b  = swz / (NBX * NBY);
    int r0 = swz % (NBX * NBY);
    int by = r0 / NBX;
    int bx = r0 - by * NBX;
    const int x0 = bx * TX, y0 = by * TY;
    const int x = x0 + tx;
    const int y = y0 + ty;                 // px A; px B = y + 4

    // Clamped global offsets for this thread's 12 staging slots (768 = 12*64)
    int goff[SPT];
#pragma unroll
    for (int k = 0; k < SPT; ++k) {
        int i = tid + NT * k;
        int r = i / LC, c = i - (i / LC) * LC;
        int gy = y0 + r - 8; gy = gy < 0 ? 0 : (gy > HH - 1 ? HH - 1 : gy);
        int gx = x0 + c - 8; gx = gx < 0 ? 0 : (gx > WW - 1 ? WW - 1 : gx);
        goff[k] = gy * WW + gx;
    }

    const uint4* hb = hp4 + (size_t)b * NG2 * HWP;

    // issue 12 async global->LDS loads for channel-plane g into lds[bb]
    auto STAGE = [&](int g, int bb) {
        const uint4* p = hb + (size_t)g * HWP;
#pragma unroll
        for (int k = 0; k < SPT; ++k)
            gl_lds16(p + goff[k], &lds[bb][tid + NT * k]);
    };

    float accA[25], accB[25];
#pragma unroll
    for (int n = 0; n < 25; ++n) { accA[n] = 0.f; accB[n] = 0.f; }
    float smA = 0.f, smB = 0.f;    // channel sums of own centers (replaces smm)

    h4 ONE;
    { h2v one2; one2.x = (__fp16)1.f; one2.y = (__fp16)1.f;
      ONE.h[0] = one2; ONE.h[1] = one2; }

    const int base = ty * LC + tx;
    auto COMPUTE = [&](int bb) {
        const uint4* L = lds[bb];
        uint4 cc0 = L[base + 8 * LC + 8];    // center px A
        uint4 cc1 = L[base + 12 * LC + 8];   // center px B
        h4 cA0, cA1, cB0, cB1;
        cA0.u.x = cc0.x; cA0.u.y = cc0.y; cA1.u.x = cc0.z; cA1.u.y = cc0.w;
        cB0.u.x = cc1.x; cB0.u.y = cc1.y; cB1.u.x = cc1.z; cB1.u.y = cc1.w;
        DOT4(smA, cA0, ONE); DOT4(smA, cA1, ONE);
        DOT4(smB, cB0, ONE); DOT4(smB, cB1, ONE);
#pragma unroll
        for (int m = 0; m < 6; ++m)
#pragma unroll
            for (int j = 0; j < 5; ++j) {
                uint4 v = L[base + (4 * m) * LC + 4 * j];
                h4 va, vb;
                va.u.x = v.x; va.u.y = v.y; vb.u.x = v.z; vb.u.y = v.w;
                if (m < 5) {
                    int n = m * 5 + j;
                    DOT4(accA[n], cA0, va);
                    DOT4(accA[n], cA1, vb);
                }
                if (m >= 1) {
                    int n = (m - 1) * 5 + j;
                    DOT4(accB[n], cB0, va);
                    DOT4(accB[n], cB1, vb);
                }
            }
    };

    // 3-deep barrier-free pipeline (single wave), rolled loop:
    //   phase g: vmcnt(24) [own loads done; g+1,g+2 in flight] -> COMPUTE(g%3)
    //            -> lgkmcnt(0) -> STAGE(g+3 -> g%3)
    STAGE(0, 0);
    STAGE(1, 1);
    STAGE(2, 2);
#pragma unroll 1
    for (int g = 0; g < NG2; ++g) {
        if (g < NG2 - 2)       { asm volatile("s_waitcnt vmcnt(24)" ::: "memory"); }
        else if (g == NG2 - 2) { asm volatile("s_waitcnt vmcnt(12)" ::: "memory"); }
        else                   { asm volatile("s_waitcnt vmcnt(0)"  ::: "memory"); }
        FENCE();
        int bb = g % 3;
        COMPUTE(bb);
        FENCE();
        if (g + 3 < NG2) {
            asm volatile("s_waitcnt lgkmcnt(0)" ::: "memory");
            STAGE(g + 3, bb);
        }
    }

    // epilogue: stage ssq tile (f32) into buffer 0 (all DMA retired)
    asm volatile("s_waitcnt lgkmcnt(0)" ::: "memory");
    float* lsq = (float*)&lds[0][0];   // 768 floats (3 KB)
    {
        const float* sp = ssq + (size_t)b * HWP;
        float r[SPT];
#pragma unroll
        for (int k = 0; k < SPT; ++k) r[k] = sp[goff[k]];
#pragma unroll
        for (int k = 0; k < SPT; ++k) lsq[tid + NT * k] = r[k];
    }
    FENCE();

    float sv[6][5];
#pragma unroll
    for (int m = 0; m < 6; ++m)
#pragma unroll
        for (int j = 0; j < 5; ++j)
            sv[m][j] = lsq[base + (4 * m) * LC + 4 * j];

    // clamped tap coords for exact-zero self taps
    int yc[6], xc[5];
#pragma unroll
    for (int m = 0; m < 6; ++m) {
        int yy = y - 8 + 4 * m; yc[m] = yy < 0 ? 0 : (yy > HH - 1 ? HH - 1 : yy);
    }
#pragma unroll
    for (int j = 0; j < 5; ++j) {
        int xx = x - 8 + 4 * j; xc[j] = xx < 0 ? 0 : (xx > WW - 1 ? WW - 1 : xx);
    }

#pragma unroll
    for (int a = 0; a < 2; ++a) {
        const int py = y + 4 * a;
        const float* acc = a ? accB : accA;
        float sm = a ? smB : smA;
        float ssA = sv[2 + a][2];
        float mu = sm * (1.0f / 64);
        float var = ssA * (1.0f / 64) - mu * mu;
        float sabs = sqrtf(fmaxf(var, 0.f));
        float L = 0.f;
#pragma unroll
        for (int m = 0; m < 5; ++m)
#pragma unroll
            for (int j = 0; j < 5; ++j) {
                float ssB = sv[m + a][j];
                float d2 = fmaxf(ssA + ssB - 2.f * acc[m * 5 + j], 0.f);
                float sq = sqrtf(d2);
                L += (yc[m + a] == py && xc[j] == x) ? 0.f : sq;
            }
        float srel = L * (1.0f / 25);
        float sraw = sabs * srel;
        out[(size_t)b * HWP + py * WW + x] = sraw / (sraw + 1.f);
    }
}

extern "C" void kernel_launch(void* const* d_in, const int* in_sizes, int n_in,
                              void* d_out, int out_size, void* d_ws, size_t ws_size,
                              hipStream_t stream) {
    const float* des = (const float*)d_in[0];
    float* out = (float*)d_out;

    uint4* hp4 = (uint4*)d_ws;                                   // BB*NG2*HWP uint4
    float* ssq = (float*)(hp4 + (size_t)BB * NG2 * HWP);         // BB*HWP

    stats_pack_k<<<dim3((BB * HWP) / 256), dim3(256), 0, stream>>>(des, hp4, ssq);
    ssd_k<<<dim3(NWG), dim3(NT), 0, stream>>>(hp4, ssq, out);
}

// Round 16
// 47.764 us; speedup vs baseline: 3.7834x; 1.1096x over previous
//
#include <hip/hip_runtime.h>

#define HH 384
#define WW 384
#define HWP (HH * WW)   // 147456
#define DD 64
#define BB 2
#define NG2 8           // 8 phases, 8 channels each

#define TX 32
#define TY 8            // tile 32x8; thread (tx,ty) ty<4 owns px (y0+ty, y0+ty+4)
#define LR 24           // TY + 16 halo rows
#define LC 48           // TX + 16 halo cols
#define LN (LR * LC)    // 1152 slots (uint4) = 18.4 KB/buffer; x2 = 36.9 KB
#define NT 128          // threads/block (2 waves)
#define SPT (LN / NT)   // 9 staging slots/thread, exact
#define NBX (WW / TX)   // 12
#define NBY (HH / TY)   // 48
#define NWG (NBX * NBY * BB)   // 1152 = 8 * 144

typedef __fp16 h2v __attribute__((ext_vector_type(2)));
union h4 { uint2 u; h2v h[2]; };

#if __has_builtin(__builtin_amdgcn_fdot2)
#define DOT4(acc, a, b)                                           \
    acc = __builtin_amdgcn_fdot2((a).h[0], (b).h[0], acc, false);   \
    acc = __builtin_amdgcn_fdot2((a).h[1], (b).h[1], acc, false)
#else
#define DOT4(acc, a, b)                                     \
    acc = fmaf((float)(a).h[0].x, (float)(b).h[0].x, acc);   \
    acc = fmaf((float)(a).h[0].y, (float)(b).h[0].y, acc);   \
    acc = fmaf((float)(a).h[1].x, (float)(b).h[1].x, acc);   \
    acc = fmaf((float)(a).h[1].y, (float)(b).h[1].y, acc)
#endif

// async global->LDS, 16B per lane (vmcnt-counted)
__device__ __forceinline__ void gl_lds16(const uint4* g, uint4* l) {
    __builtin_amdgcn_global_load_lds(
        (const __attribute__((address_space(1))) unsigned int*)(const void*)g,
        (__attribute__((address_space(3))) unsigned int*)(void*)l, 16, 0, 0);
}

#define FENCE() asm volatile("" ::: "memory")

// K1: stats + repack to f16 8-channel planes hp4[b][g2][y][x] (16 B / px)
__global__ __launch_bounds__(256) void stats_pack_k(const float* __restrict__ des,
                                                    uint4* __restrict__ hp4,
                                                    float* __restrict__ ssq,
                                                    float* __restrict__ smm) {
    int idx = blockIdx.x * 256 + threadIdx.x;        // 0 .. 294911
    int b = idx / HWP;
    int p = idx - b * HWP;
    const float* base = des + (size_t)b * DD * HWP + p;
    uint4* hb = hp4 + (size_t)b * NG2 * HWP + p;
    float ss = 0.f, s0 = 0.f;
#pragma unroll 2
    for (int g = 0; g < NG2; ++g) {
        float v0 = base[(size_t)(8 * g + 0) * HWP];
        float v1 = base[(size_t)(8 * g + 1) * HWP];
        float v2 = base[(size_t)(8 * g + 2) * HWP];
        float v3 = base[(size_t)(8 * g + 3) * HWP];
        float v4 = base[(size_t)(8 * g + 4) * HWP];
        float v5 = base[(size_t)(8 * g + 5) * HWP];
        float v6 = base[(size_t)(8 * g + 6) * HWP];
        float v7 = base[(size_t)(8 * g + 7) * HWP];
        ss = fmaf(v0, v0, ss); ss = fmaf(v1, v1, ss);
        ss = fmaf(v2, v2, ss); ss = fmaf(v3, v3, ss);
        ss = fmaf(v4, v4, ss); ss = fmaf(v5, v5, ss);
        ss = fmaf(v6, v6, ss); ss = fmaf(v7, v7, ss);
        s0 += ((v0 + v1) + (v2 + v3)) + ((v4 + v5) + (v6 + v7));
        h4 a, c;
        a.h[0] = __builtin_amdgcn_cvt_pkrtz(v0, v1);
        a.h[1] = __builtin_amdgcn_cvt_pkrtz(v2, v3);
        c.h[0] = __builtin_amdgcn_cvt_pkrtz(v4, v5);
        c.h[1] = __builtin_amdgcn_cvt_pkrtz(v6, v7);
        uint4 w; w.x = a.u.x; w.y = a.u.y; w.z = c.u.x; w.w = c.u.y;
        hb[(size_t)g * HWP] = w;
    }
    ssq[idx] = ss;
    smm[idx] = s0;
}

// K2: dilated 5x5 dot stencil, 2 px/thread (y, y+4) sharing 5/6 tap rows.
// Tile 32x8, 128 threads, f16 b128 LDS double-buffer, 8 phases.
// Staging via global_load_lds + counted vmcnt: next phase's 9 loads stay in
// flight across both barriers (no per-phase vmcnt(0) drain).
// Phase loop MUST stay "#pragma unroll 1" (full unroll -> VGPR spill, R14).
__global__ __launch_bounds__(NT) void ssd_k(const uint4* __restrict__ hp4,
                                            const float* __restrict__ ssq,
                                            const float* __restrict__ smm,
                                            float* __restrict__ out) {
    __shared__ uint4 lds[2][LN];   // 36,864 B
    const int tx = threadIdx.x;            // 0..31
    const int ty = threadIdx.y;            // 0..3
    const int tid = ty * 32 + tx;

    // XCD-aware bijective swizzle (1152 = 8 * 144)
    int bid = blockIdx.x;
    int swz = (bid & 7) * 144 + (bid >> 3);
    int b  = swz / (NBX * NBY);
    int r0 = swz % (NBX * NBY);
    int by = r0 / NBX;
    int bx = r0 - by * NBX;
    const int x0 = bx * TX, y0 = by * TY;
    const int x = x0 + tx;
    const int y = y0 + ty;                 // px A; px B = y + 4

    // Clamped global offsets for this thread's 9 staging slots (1152 = 9*128)
    int goff[SPT];
#pragma unroll
    for (int k = 0; k < SPT; ++k) {
        int i = tid + NT * k;
        int r = i / LC, c = i - (i / LC) * LC;
        int gy = y0 + r - 8; gy = gy < 0 ? 0 : (gy > HH - 1 ? HH - 1 : gy);
        int gx = x0 + c - 8; gx = gx < 0 ? 0 : (gx > WW - 1 ? WW - 1 : gx);
        goff[k] = gy * WW + gx;
    }

    const uint4* hb = hp4 + (size_t)b * NG2 * HWP;

    // issue 9 async global->LDS loads for channel-plane g into lds[bb]
    auto STAGE = [&](int g, int bb) {
        const uint4* p = hb + (size_t)g * HWP;
#pragma unroll
        for (int k = 0; k < SPT; ++k)
            gl_lds16(p + goff[k], &lds[bb][tid + NT * k]);
    };

    float accA[25], accB[25];
#pragma unroll
    for (int n = 0; n < 25; ++n) { accA[n] = 0.f; accB[n] = 0.f; }

    const int base = ty * LC + tx;
    auto COMPUTE = [&](int bb) {
        const uint4* L = lds[bb];
        uint4 cc0 = L[base + 8 * LC + 8];    // center px A
        uint4 cc1 = L[base + 12 * LC + 8];   // center px B
        h4 cA0, cA1, cB0, cB1;
        cA0.u.x = cc0.x; cA0.u.y = cc0.y; cA1.u.x = cc0.z; cA1.u.y = cc0.w;
        cB0.u.x = cc1.x; cB0.u.y = cc1.y; cB1.u.x = cc1.z; cB1.u.y = cc1.w;
#pragma unroll
        for (int m = 0; m < 6; ++m)
#pragma unroll
            for (int j = 0; j < 5; ++j) {
                uint4 v = L[base + (4 * m) * LC + 4 * j];
                h4 va, vb;
                va.u.x = v.x; va.u.y = v.y; vb.u.x = v.z; vb.u.y = v.w;
                if (m < 5) {
                    int n = m * 5 + j;
                    DOT4(accA[n], cA0, va);
                    DOT4(accA[n], cA1, vb);
                }
                if (m >= 1) {
                    int n = (m - 1) * 5 + j;
                    DOT4(accB[n], cB0, va);
                    DOT4(accB[n], cB1, vb);
                }
            }
    };

    // 2-deep async pipeline, counted vmcnt, raw barriers:
    //   phase g: wait own 9 g-loads (vmcnt<=9: g+1's stay in flight); barrier;
    //            COMPUTE(g&1); barrier; issue STAGE(g+2 -> g&1)
    STAGE(0, 0);
    STAGE(1, 1);
#pragma unroll 1
    for (int g = 0; g < NG2; ++g) {
        if (g < NG2 - 1) { asm volatile("s_waitcnt vmcnt(9)" ::: "memory"); }
        else             { asm volatile("s_waitcnt vmcnt(0)" ::: "memory"); }
        __builtin_amdgcn_s_barrier();
        FENCE();
        COMPUTE(g & 1);
        FENCE();
        __builtin_amdgcn_s_barrier();
        FENCE();
        if (g + 2 < NG2) STAGE(g + 2, g & 1);
    }

    // epilogue: stage ssq tile (f32) into buffer 0 (nothing in flight now)
    float* lsq = (float*)&lds[0][0];   // 1152 floats (4.6 KB)
    {
        const float* sp = ssq + (size_t)b * HWP;
        float r[SPT];
#pragma unroll
        for (int k = 0; k < SPT; ++k) r[k] = sp[goff[k]];
#pragma unroll
        for (int k = 0; k < SPT; ++k) lsq[tid + NT * k] = r[k];
    }
    __syncthreads();

    float sv[6][5];
#pragma unroll
    for (int m = 0; m < 6; ++m)
#pragma unroll
        for (int j = 0; j < 5; ++j)
            sv[m][j] = lsq[base + (4 * m) * LC + 4 * j];

    // clamped tap coords for exact-zero self taps
    int yc[6], xc[5];
#pragma unroll
    for (int m = 0; m < 6; ++m) {
        int yy = y - 8 + 4 * m; yc[m] = yy < 0 ? 0 : (yy > HH - 1 ? HH - 1 : yy);
    }
#pragma unroll
    for (int j = 0; j < 5; ++j) {
        int xx = x - 8 + 4 * j; xc[j] = xx < 0 ? 0 : (xx > WW - 1 ? WW - 1 : xx);
    }

#pragma unroll
    for (int a = 0; a < 2; ++a) {
        const int py = y + 4 * a;
        const float* acc = a ? accB : accA;
        float ssA = sv[2 + a][2];
        float mu = smm[(size_t)b * HWP + py * WW + x] * (1.0f / 64);
        float var = ssA * (1.0f / 64) - mu * mu;
        float sabs = sqrtf(fmaxf(var, 0.f));
        float L = 0.f;
#pragma unroll
        for (int m = 0; m < 5; ++m)
#pragma unroll
            for (int j = 0; j < 5; ++j) {
                float ssB = sv[m + a][j];
                float d2 = fmaxf(ssA + ssB - 2.f * acc[m * 5 + j], 0.f);
                float sq = sqrtf(d2);
                L += (yc[m + a] == py && xc[j] == x) ? 0.f : sq;
            }
        float srel = L * (1.0f / 25);
        float sraw = sabs * srel;
        out[(size_t)b * HWP + py * WW + x] = sraw / (sraw + 1.f);
    }
}

extern "C" void kernel_launch(void* const* d_in, const int* in_sizes, int n_in,
                              void* d_out, int out_size, void* d_ws, size_t ws_size,
                              hipStream_t stream) {
    const float* des = (const float*)d_in[0];
    float* out = (float*)d_out;

    uint4* hp4 = (uint4*)d_ws;                                   // BB*NG2*HWP uint4
    float* ssq = (float*)(hp4 + (size_t)BB * NG2 * HWP);         // BB*HWP
    float* smm = ssq + (size_t)BB * HWP;                         // BB*HWP

    stats_pack_k<<<dim3((BB * HWP) / 256), dim3(256), 0, stream>>>(des, hp4, ssq, smm);
    ssd_k<<<dim3(NWG), dim3(TX, 4), 0, stream>>>(hp4, ssq, smm, out);
}